// Round 1
// baseline (922.400 us; speedup 1.0000x reference)
//
#include <hip/hip_runtime.h>
#include <math.h>

#define NB 16
#define NC 256
#define NL 1024
#define NDI 512
#define NDS 64
#define NDTR 16
#define MTOT (NB*NL)   // 16384

__device__ __forceinline__ float sigmoidf_(float x){ return 1.f/(1.f+__expf(-x)); }

// ---------------- weight pre-transposes (tiny) ----------------
// Wt[k*N + n] = W[n*K + k]
__global__ void transpose_w_k(const float* __restrict__ W, float* __restrict__ Wt, int N, int K){
  int idx = blockIdx.x*256 + threadIdx.x;
  if (idx >= N*K) return;
  int n = idx % N, k = idx / N;
  Wt[idx] = W[(size_t)n*K + k];
}

// gate_w (co, ci, tap) -> gwt[(tap*256+ci)*256 + co]
__global__ void transpose_gw_k(const float* __restrict__ gw, float* __restrict__ gwt){
  int idx = blockIdx.x*256 + threadIdx.x; // 768*256
  if (idx >= 768*256) return;
  int co = idx & 255; int k = idx >> 8;
  int tap = k >> 8; int ci = k & 255;
  gwt[idx] = gw[co*768 + ci*3 + tap];
}

// ---------------- K0: xs[b,l,c] = x[b,c,l] + rel_h[c, l&31] + rel_w[c, l>>5]
__global__ __launch_bounds__(256) void k0_xs(const float* __restrict__ x,
                                             const float* __restrict__ rel_h,
                                             const float* __restrict__ rel_w,
                                             float* __restrict__ xs){
  __shared__ float tile[32][33];
  int b = blockIdx.z, c0 = blockIdx.y*32, l0 = blockIdx.x*32;
  int tid = threadIdx.x;
  int j = tid & 31, i0 = tid >> 5;       // i0 0..7
#pragma unroll
  for (int r = 0; r < 4; ++r) {
    int i = i0 + r*8;
    tile[i][j] = x[((size_t)(b*NC + c0 + i))*NL + l0 + j];
  }
  __syncthreads();
  int cl = tid & 31, lq = tid >> 5;
#pragma unroll
  for (int r = 0; r < 4; ++r) {
    int ll = lq + r*8;
    int l = l0 + ll, c = c0 + cl;
    xs[((size_t)(b*NL + l))*NC + c] = tile[cl][ll] + rel_h[c*32 + (l & 31)] + rel_w[c*32 + (l >> 5)];
  }
}

// ---------------- generic 64x64 tiled GEMM: C[m,n] = sum_k A[m,k]*Wt[k,n]
// A is (MTOT, K) row-major (or conv-gathered xs when CONVA); Wt is (K, N) row-major.
enum { EPI_STORE=0, EPI_SPLIT=1, EPI_SIGB=2, EPI_MUL=3 };

template<int EPI, bool CONVA>
__global__ __launch_bounds__(256) void gemm64_k(
    const float* __restrict__ A, const float* __restrict__ Wt,
    const float* __restrict__ bias, const float* __restrict__ aux,
    float* __restrict__ out0, float* __restrict__ out1,
    int N, int K)
{
  __shared__ float As[16][68];
  __shared__ float Bs[16][68];
  const int tid = threadIdx.x;
  const int m0 = blockIdx.x * 64;
  const int n0 = blockIdx.y * 64;
  const int tx = tid & 15, ty = tid >> 4;
  const int lm = tid >> 2, lk = (tid & 3) * 4;    // A tile: row lm, k-offset lk
  const int bk = tid >> 4, bn = (tid & 15) * 4;   // B tile: k-row bk, n-offset bn
  float acc[4][4] = {};

  for (int k0 = 0; k0 < K; k0 += 16) {
    float4 av;
    if (CONVA) {
      // logical k = tap*256 + ci over xs; output l uses input l+tap-1 (pad 1)
      int kg = k0 + lk;
      int tap = kg >> 8, ci = kg & 255;
      int m = m0 + lm;
      int l = m & (NL-1);
      int lp = l + tap - 1;
      if (lp >= 0 && lp < NL)
        av = *reinterpret_cast<const float4*>(&A[(size_t)(m + tap - 1) * NC + ci]);
      else
        av = make_float4(0.f,0.f,0.f,0.f);
    } else {
      av = *reinterpret_cast<const float4*>(&A[(size_t)(m0 + lm) * K + k0 + lk]);
    }
    As[lk+0][lm]=av.x; As[lk+1][lm]=av.y; As[lk+2][lm]=av.z; As[lk+3][lm]=av.w;

    float4 bv = make_float4(0.f,0.f,0.f,0.f);
    if (n0 + bn < N)
      bv = *reinterpret_cast<const float4*>(&Wt[(size_t)(k0 + bk) * N + n0 + bn]);
    *reinterpret_cast<float4*>(&Bs[bk][bn]) = bv;
    __syncthreads();
#pragma unroll
    for (int kk = 0; kk < 16; ++kk) {
      float4 a  = *reinterpret_cast<const float4*>(&As[kk][ty*4]);
      float4 bq = *reinterpret_cast<const float4*>(&Bs[kk][tx*4]);
      float a4[4] = {a.x,a.y,a.z,a.w};
      float b4[4] = {bq.x,bq.y,bq.z,bq.w};
#pragma unroll
      for (int i = 0; i < 4; ++i)
#pragma unroll
        for (int jj = 0; jj < 4; ++jj)
          acc[i][jj] += a4[i]*b4[jj];
    }
    __syncthreads();
  }

#pragma unroll
  for (int i = 0; i < 4; ++i) {
    int m = m0 + ty*4 + i;
    int nbase = n0 + tx*4;
    if (EPI == EPI_STORE) {
      if (nbase < N) {
        float4 v = make_float4(acc[i][0],acc[i][1],acc[i][2],acc[i][3]);
        *reinterpret_cast<float4*>(&out0[(size_t)m*N + nbase]) = v;
      }
    } else if (EPI == EPI_SPLIT) {
      float4 v = make_float4(acc[i][0],acc[i][1],acc[i][2],acc[i][3]);
      if (n0 < NDI)
        *reinterpret_cast<float4*>(&out0[(size_t)m*NDI + nbase]) = v;
      else
        *reinterpret_cast<float4*>(&out1[(size_t)m*NDI + nbase - NDI]) = v;
    } else if (EPI == EPI_SIGB) {
      float4 v;
      v.x = sigmoidf_(acc[i][0] + bias[nbase+0]);
      v.y = sigmoidf_(acc[i][1] + bias[nbase+1]);
      v.z = sigmoidf_(acc[i][2] + bias[nbase+2]);
      v.w = sigmoidf_(acc[i][3] + bias[nbase+3]);
      *reinterpret_cast<float4*>(&out0[(size_t)m*N + nbase]) = v;
    } else { // EPI_MUL
      float4 cx = *reinterpret_cast<const float4*>(&aux[(size_t)m*N + nbase]);
      float4 v = make_float4(acc[i][0]*cx.x, acc[i][1]*cx.y, acc[i][2]*cx.z, acc[i][3]*cx.w);
      *reinterpret_cast<float4*>(&out0[(size_t)m*N + nbase]) = v;
    }
  }
}

// ---------------- K3: depthwise causal conv (k=4) + silu
__global__ __launch_bounds__(256) void k3_dwconv(const float* __restrict__ u_raw,
                                                 const float* __restrict__ cw,
                                                 const float* __restrict__ cb,
                                                 float* __restrict__ up){
  int idx = blockIdx.x*256 + threadIdx.x;   // B*L*DI
  int d = idx & (NDI-1);
  int bl = idx >> 9;
  int l = bl & (NL-1);
  float acc = cb[d];
#pragma unroll
  for (int t = 0; t < 4; ++t) {
    int lp = l - 3 + t;
    if (lp >= 0) acc += u_raw[(size_t)(bl - 3 + t)*NDI + d] * cw[d*4 + t];
  }
  up[idx] = acc * sigmoidf_(acc);  // silu
}

// ---------------- K5: delta = softplus(dt @ dt_proj_w.T + b)
__global__ __launch_bounds__(256) void k5_delta(const float* __restrict__ xdbl,
                                                const float* __restrict__ dtw,
                                                const float* __restrict__ dtb,
                                                float* __restrict__ delta){
  int idx = blockIdx.x*256 + threadIdx.x;   // B*L*DI
  int di = idx & (NDI-1);
  int m = idx >> 9;
  const float* dtp = xdbl + (size_t)m*144;
  float acc = dtb[di];
#pragma unroll
  for (int r = 0; r < 16; ++r) acc += dtp[r] * dtw[di*16 + r];
  delta[idx] = (acc > 20.f) ? acc : log1pf(__expf(acc));
}

// ---------------- K6: selective scan, fused (ys + u*D)*silu(z)
// block = 256 thr = 32 d * 8 lanes; grid = (DI/32, B)
__global__ __launch_bounds__(256) void k6_scan(
    const float* __restrict__ delta, const float* __restrict__ up,
    const float* __restrict__ xdbl, const float* __restrict__ zbuf,
    const float* __restrict__ A_log, const float* __restrict__ Dvec,
    float* __restrict__ yg)
{
  int tid = threadIdx.x;
  int t8 = tid & 7;
  int dloc = tid >> 3;                 // 0..31
  int b = blockIdx.y;
  int d = blockIdx.x * 32 + dloc;
  int nbase = t8 * 8;

  float a[8], h[8] = {0,0,0,0,0,0,0,0};
#pragma unroll
  for (int j = 0; j < 8; ++j) a[j] = -__expf(A_log[d*NDS + nbase + j]);
  float Dd = Dvec[d];

  const float* dp  = delta + ((size_t)b*NL)*NDI + d;
  const float* upp = up    + ((size_t)b*NL)*NDI + d;
  const float* zp  = zbuf  + ((size_t)b*NL)*NDI + d;
  const float* xb  = xdbl  + ((size_t)b*NL)*144;
  float*       ygp = yg    + ((size_t)b*NL)*NDI + d;

  // prefetch step 0
  float dv = dp[0], uv = upp[0], zv = zp[0];
  float4 b0 = *(const float4*)(xb + 16 + nbase);
  float4 b1 = *(const float4*)(xb + 16 + nbase + 4);
  float4 c0 = *(const float4*)(xb + 80 + nbase);
  float4 c1 = *(const float4*)(xb + 80 + nbase + 4);

  for (int l = 0; l < NL; ++l) {
    float dv_c = dv, uv_c = uv, zv_c = zv;
    float4 B0 = b0, B1 = b1, C0 = c0, C1 = c1;
    if (l < NL-1) {
      dv = dp[(l+1)*NDI]; uv = upp[(l+1)*NDI]; zv = zp[(l+1)*NDI];
      const float* xr = xb + (size_t)(l+1)*144;
      b0 = *(const float4*)(xr + 16 + nbase);
      b1 = *(const float4*)(xr + 16 + nbase + 4);
      c0 = *(const float4*)(xr + 80 + nbase);
      c1 = *(const float4*)(xr + 80 + nbase + 4);
    }
    float du = dv_c * uv_c;
    float Bv[8] = {B0.x,B0.y,B0.z,B0.w,B1.x,B1.y,B1.z,B1.w};
    float Cv[8] = {C0.x,C0.y,C0.z,C0.w,C1.x,C1.y,C1.z,C1.w};
    float acc = 0.f;
#pragma unroll
    for (int j = 0; j < 8; ++j) {
      h[j] = __expf(dv_c * a[j]) * h[j] + du * Bv[j];
      acc += h[j] * Cv[j];
    }
    acc += __shfl_xor(acc, 1, 64);
    acc += __shfl_xor(acc, 2, 64);
    acc += __shfl_xor(acc, 4, 64);
    if (t8 == 0) {
      float y = acc + uv_c * Dd;
      ygp[(size_t)l*NDI] = y * (zv_c * sigmoidf_(zv_c));
    }
  }
}

extern "C" void kernel_launch(void* const* d_in, const int* in_sizes, int n_in,
                              void* d_out, int out_size, void* d_ws, size_t ws_size,
                              hipStream_t stream)
{
  const float* x      = (const float*)d_in[0];
  const float* rel_h  = (const float*)d_in[1];
  const float* rel_w  = (const float*)d_in[2];
  const float* gate_w = (const float*)d_in[3];
  const float* gate_b = (const float*)d_in[4];
  const float* ipw    = (const float*)d_in[5];
  const float* conv_w = (const float*)d_in[6];
  const float* conv_b = (const float*)d_in[7];
  const float* xpw    = (const float*)d_in[8];
  const float* dtw    = (const float*)d_in[9];
  const float* dtb    = (const float*)d_in[10];
  const float* A_log  = (const float*)d_in[11];
  const float* Dv     = (const float*)d_in[12];
  const float* opw    = (const float*)d_in[13];

  float* ws = (float*)d_ws;
  float* xs    = ws;                  // 4,194,304
  float* ctx   = xs    + 4194304;     // 4,194,304
  float* u_raw = ctx   + 4194304;     // 8,388,608  (reused as ygated after dwconv)
  float* zbuf  = u_raw + 8388608;     // 8,388,608
  float* up    = zbuf  + 8388608;     // 8,388,608
  float* xdbl  = up    + 8388608;     // 2,359,296
  float* delta = xdbl  + 2359296;     // 8,388,608
  float* gwt   = delta + 8388608;     // 196,608
  float* ipwt  = gwt   + 196608;      // 262,144
  float* xpwt  = ipwt  + 262144;      // 73,728
  float* opwt  = xpwt  + 73728;       // 131,072
  float* ygated = u_raw;              // alias: u_raw dead after k3_dwconv

  transpose_gw_k<<<768, 256, 0, stream>>>(gate_w, gwt);
  transpose_w_k<<<(1024*256+255)/256, 256, 0, stream>>>(ipw, ipwt, 1024, 256);
  transpose_w_k<<<(144*512+255)/256, 256, 0, stream>>>(xpw, xpwt, 144, 512);
  transpose_w_k<<<(256*512+255)/256, 256, 0, stream>>>(opw, opwt, 256, 512);

  k0_xs<<<dim3(32,8,16), 256, 0, stream>>>(x, rel_h, rel_w, xs);

  // ctx = sigmoid(conv3(xs) + gate_b)
  gemm64_k<EPI_SIGB, true><<<dim3(MTOT/64, 4), 256, 0, stream>>>(
      xs, gwt, gate_b, nullptr, ctx, nullptr, 256, 768);

  // xz = xs @ in_proj_w.T -> u_raw | zbuf
  gemm64_k<EPI_SPLIT, false><<<dim3(MTOT/64, 16), 256, 0, stream>>>(
      xs, ipwt, nullptr, nullptr, u_raw, zbuf, 1024, 256);

  // u' = silu(depthwise_conv(u_raw))
  k3_dwconv<<<(NB*NL*NDI)/256, 256, 0, stream>>>(u_raw, conv_w, conv_b, up);

  // x_dbl = u' @ x_proj_w.T   (N=144)
  gemm64_k<EPI_STORE, false><<<dim3(MTOT/64, 3), 256, 0, stream>>>(
      up, xpwt, nullptr, nullptr, xdbl, nullptr, 144, 512);

  // delta = softplus(dt @ dt_proj_w.T + dt_proj_b)
  k5_delta<<<(NB*NL*NDI)/256, 256, 0, stream>>>(xdbl, dtw, dtb, delta);

  // selective scan + (y + u*D)*silu(z)
  k6_scan<<<dim3(NDI/32, NB), 256, 0, stream>>>(delta, up, xdbl, zbuf, A_log, Dv, ygated);

  // out = (ygated @ out_proj_w.T) * ctx
  gemm64_k<EPI_MUL, false><<<dim3(MTOT/64, 4), 256, 0, stream>>>(
      ygated, opwt, nullptr, ctx, (float*)d_out, nullptr, 256, 512);
}